// Round 3
// baseline (409.299 us; speedup 1.0000x reference)
//
#include <hip/hip_runtime.h>

// LaneATT head, MI355X. Pipeline:
//  prep -> conv1x1 -> gather(baf bf16 [B][1024][768]) -> GEMM1 (256^2 2-phase) ->
//  softmax+shift -> transpose -> GEMM2 (256^2 2-phase, batched) -> GEMM3 + epilogue.
// ws layout unchanged from round 1 (total 221,617,152 bytes).

typedef unsigned short u16;
typedef short short8 __attribute__((ext_vector_type(8)));
typedef float f32x4 __attribute__((ext_vector_type(4)));

__device__ __forceinline__ u16 f2bf(float f) {
    union { float f; unsigned u; } v; v.f = f;
    unsigned r = v.u + 0x7FFFu + ((v.u >> 16) & 1u);
    return (u16)(r >> 16);
}
__device__ __forceinline__ float bf2f(u16 u) {
    union { unsigned u; float f; } v; v.u = ((unsigned)u) << 16;
    return v.f;
}

// async global->LDS, 16B per lane; lds dest must be wave-uniform-base + lane*16B.
__device__ __forceinline__ void gload16(const u16* gsrc, u16* ldst) {
    __builtin_amdgcn_global_load_lds(
        (const __attribute__((address_space(1))) unsigned int*)gsrc,
        (__attribute__((address_space(3))) unsigned int*)ldst, 16, 0, 0);
}

// ---------- prep kernels ----------

__global__ __launch_bounds__(256) void k_prep_attnw(const float* __restrict__ attn_w,
                                                    u16* __restrict__ attn_wb) {
    int i = blockIdx.x * 256 + threadIdx.x;          // over 1024*704
    if (i >= 1024 * 704) return;
    int r = i / 704;
    attn_wb[i] = (r < 999) ? f2bf(attn_w[i]) : (u16)0;
}

__global__ __launch_bounds__(256) void k_prep_wcat(const float* __restrict__ cls_w,
                                                   const float* __restrict__ reg_w,
                                                   u16* __restrict__ wcat) {
    int i = blockIdx.x * 256 + threadIdx.x;          // over 80*1408
    if (i >= 80 * 1408) return;
    int o = i / 1408, k = i - o * 1408;
    float v = 0.f;
    if (o < 2) v = cls_w[o * 1408 + k];
    else if (o < 75) v = reg_w[(o - 2) * 1408 + k];
    wcat[i] = f2bf(v);
}

__global__ __launch_bounds__(256) void k_detect_mask(const unsigned char* __restrict__ mask,
                                                     int* __restrict__ flag) {
    int any = 0;
    for (int i = threadIdx.x; i < 11000; i += 256)
        if ((i & 3) && mask[i]) any = 1;
    any = __any(any) ? 1 : 0;
    __shared__ int sh[4];
    if ((threadIdx.x & 63) == 0) sh[threadIdx.x >> 6] = any;
    __syncthreads();
    if (threadIdx.x == 0) *flag = sh[0] | sh[1] | sh[2] | sh[3];
}

__global__ __launch_bounds__(256) void k_prep_xn(const int* __restrict__ cut_xs,
                                                 const void* __restrict__ mask,
                                                 const int* __restrict__ flag,
                                                 int* __restrict__ xn) {
    int i = blockIdx.x * 256 + threadIdx.x;          // over 11000 = (n,y)
    if (i >= 11000) return;
    int inv = (*flag) ? (int)((const unsigned char*)mask)[i]
                      : ((const int*)mask)[i];
    int n = i / 11, y = i - n * 11;
    xn[i] = inv ? -1 : cut_xs[n * 704 + y];
}

// ---------- conv 1x1 ----------
__global__ __launch_bounds__(256) void k_conv(const float* __restrict__ x,
                                              const float* __restrict__ w1,
                                              const float* __restrict__ b1,
                                              float* __restrict__ feat) {
    __shared__ float wl[4][512];
    const int b = blockIdx.x, og = blockIdx.y;
    for (int i = threadIdx.x; i < 4 * 512; i += 256)
        wl[i >> 9][i & 511] = w1[(og * 4 + (i >> 9)) * 512 + (i & 511)];
    __syncthreads();
    const int p = threadIdx.x;
    if (p >= 220) return;
    const float* xb = x + (size_t)b * 512 * 220 + p;
    float a0 = 0.f, a1 = 0.f, a2 = 0.f, a3 = 0.f;
    #pragma unroll 4
    for (int c = 0; c < 512; ++c) {
        float xv = xb[(size_t)c * 220];
        a0 = fmaf(xv, wl[0][c], a0);
        a1 = fmaf(xv, wl[1][c], a1);
        a2 = fmaf(xv, wl[2][c], a2);
        a3 = fmaf(xv, wl[3][c], a3);
    }
    float* fo = feat + (size_t)b * 14080 + (og * 4) * 220 + p;
    fo[0]   = a0 + b1[og * 4 + 0];
    fo[220] = a1 + b1[og * 4 + 1];
    fo[440] = a2 + b1[og * 4 + 2];
    fo[660] = a3 + b1[og * 4 + 3];
}

// ---------- gather -> baf (bf16, [B][1024][768], pads zeroed), short8 stores ----------
__global__ __launch_bounds__(384) void k_gather(const float* __restrict__ feat,
                                                const int* __restrict__ xn,
                                                u16* __restrict__ baf) {
    const int b = blockIdx.y, t = threadIdx.x;
    const int a = t / 96, r = t - a * 96;
    const int n = blockIdx.x * 4 + a;
    const int d8 = r * 8;
    const float* fb = feat + (size_t)b * 14080;
    short8 o = {0, 0, 0, 0, 0, 0, 0, 0};
    #pragma unroll
    for (int j = 0; j < 8; ++j) {
        int d = d8 + j;
        float v = 0.f;
        if (n < 1000 && d < 704) {
            int c = d / 11, y = d - c * 11;
            int xv = xn[n * 11 + y];
            if (xv >= 0) v = fb[c * 220 + y * 20 + xv];
        }
        o[j] = (short)f2bf(v);
    }
    *(short8*)&baf[((size_t)b * 1024 + n) * 768 + d8] = o;
}

// ---------- 256x256-tile bf16 GEMM, 2-phase counted pipeline ----------
// C = A(MxK) * Bt(NrowsxK)^T, all row-major bf16; 512 threads = 8 waves (2x4).
__global__ __launch_bounds__(512) void k_gemm256(const u16* __restrict__ A, long sAb, int lda,
                                                 const u16* __restrict__ Bt, long sBb, int ldb,
                                                 u16* __restrict__ C, long sCb, int ldc,
                                                 int ntN, int tilesPerBatch, int nwg, int ksteps) {
    __shared__ __attribute__((aligned(16))) u16 Al[2][8192];  // 2 x 256x32
    __shared__ __attribute__((aligned(16))) u16 Bl[2][8192];
    const int bid = blockIdx.x;
    const int cpx = nwg >> 3;                       // bijective XCD swizzle (nwg%8==0)
    const int logical = (bid & 7) * cpx + (bid >> 3);
    const int batch = logical / tilesPerBatch;
    const int t = logical - batch * tilesPerBatch;
    const int tM = t / ntN, tN = t - tM * ntN;
    A  += (size_t)batch * sAb;
    Bt += (size_t)batch * sBb;
    C  += (size_t)batch * sCb;

    const int tid = threadIdx.x;
    const int lane = tid & 63, w = tid >> 6;
    const int wr = w >> 2, wc = w & 3;              // wave tile: rows wr*128, cols wc*64
    const int l15 = lane & 15, lk = (lane >> 4) * 8;
    const u16* Abase = A + (size_t)tM * 256 * lda;
    const u16* Bbase = Bt + (size_t)tN * 256 * ldb;
    const int srow = tid >> 2, scol = (tid & 3) * 8;  // staging: 128 rows/issue

    f32x4 acc[8][4] = {};

    auto STAGE = [&](int bi, int kt) {
        const int k0 = kt * 32;
        #pragma unroll
        for (int j = 0; j < 2; ++j) {
            gload16(Abase + (size_t)(j * 128 + srow) * lda + k0 + scol,
                    &Al[bi][j * 4096 + tid * 8]);
            gload16(Bbase + (size_t)(j * 128 + srow) * ldb + k0 + scol,
                    &Bl[bi][j * 4096 + tid * 8]);
        }
    };
    auto COMPUTE = [&](int bi) {
        short8 af[8], bv[4];
        #pragma unroll
        for (int m = 0; m < 8; ++m)
            af[m] = *(const short8*)&Al[bi][(wr * 128 + m * 16 + l15) * 32 + lk];
        #pragma unroll
        for (int n = 0; n < 4; ++n)
            bv[n] = *(const short8*)&Bl[bi][(wc * 64 + n * 16 + l15) * 32 + lk];
        #pragma unroll
        for (int m = 0; m < 8; ++m)
            #pragma unroll
            for (int n = 0; n < 4; ++n)
                acc[m][n] = __builtin_amdgcn_mfma_f32_16x16x32_bf16(af[m], bv[n], acc[m][n], 0, 0, 0);
    };

    STAGE(0, 0);
    __syncthreads();                                 // vmcnt(0) drain + barrier
    int cur = 0;
    for (int kt = 0; kt < ksteps - 1; ++kt) {
        STAGE(cur ^ 1, kt + 1);                      // async prefetch next K-tile
        COMPUTE(cur);                                // MFMA on current
        __syncthreads();
        cur ^= 1;
    }
    COMPUTE(cur);

    const int rb = tM * 256 + wr * 128 + ((lane >> 4) << 2);
    const int cb = tN * 256 + wc * 64 + l15;
    #pragma unroll
    for (int m = 0; m < 8; ++m)
        #pragma unroll
        for (int n = 0; n < 4; ++n)
            #pragma unroll
            for (int j = 0; j < 4; ++j)
                C[(size_t)(rb + m * 16 + j) * ldc + cb + n * 16] = f2bf(acc[m][n][j]);
}

// ---------- softmax + diagonal-shift, 1 row per 128-thread block, short8 ----------
__global__ __launch_bounds__(128) void k_softmax(u16* __restrict__ att,
                                                 const float* __restrict__ attn_b) {
    __shared__ float sv[1000];
    __shared__ float red[2], red2[2];
    const int row = blockIdx.x;
    const int n = row & 1023;
    u16* __restrict__ r = att + (size_t)row * 1024;
    const int tid = threadIdx.x, c8 = tid * 8;
    if (n >= 1000) {
        short8 z = {0, 0, 0, 0, 0, 0, 0, 0};
        *(short8*)&r[c8] = z;
        return;
    }
    short8 v = *(const short8*)&r[c8];
    float f[8];
    float lmax = -1e30f;
    #pragma unroll
    for (int j = 0; j < 8; ++j) {
        int c = c8 + j;
        f[j] = (c < 999) ? bf2f((u16)v[j]) + attn_b[c] : -1e30f;
        lmax = fmaxf(lmax, f[j]);
    }
    #pragma unroll
    for (int o = 32; o > 0; o >>= 1) lmax = fmaxf(lmax, __shfl_xor(lmax, o));
    if ((tid & 63) == 0) red[tid >> 6] = lmax;
    __syncthreads();
    float gmax = fmaxf(red[0], red[1]);
    float lsum = 0.f;
    #pragma unroll
    for (int j = 0; j < 8; ++j) {
        int c = c8 + j;
        float e = (c < 999) ? __expf(f[j] - gmax) : 0.f;
        if (c < 999) sv[c] = e;
        lsum += e;
    }
    #pragma unroll
    for (int o = 32; o > 0; o >>= 1) lsum += __shfl_xor(lsum, o);
    if ((tid & 63) == 0) red2[tid >> 6] = lsum;
    __syncthreads();                                 // also orders sv[] writes
    float inv = 1.f / (red2[0] + red2[1]);
    short8 o;
    #pragma unroll
    for (int j = 0; j < 8; ++j) {
        int c = c8 + j;
        float val = 0.f;
        if (c < 1000 && c != n) val = sv[c - (c > n ? 1 : 0)] * inv;
        o[j] = (short)f2bf(val);
    }
    *(short8*)&r[c8] = o;
}

// ---------- baf transpose: bafT[b][d][m] = baf[b][m][d], xor-swizzled LDS ----------
__global__ __launch_bounds__(256) void k_transpose(const u16* __restrict__ baf,
                                                   u16* __restrict__ bafT) {
    __shared__ __attribute__((aligned(16))) u16 t[64 * 64];
    const int mt = blockIdx.x & 15, dt = blockIdx.x >> 4;
    const int b = blockIdx.y;
    const int tid = threadIdx.x;
    const u16* src = baf + ((size_t)b * 1024 + mt * 64) * 768 + dt * 64;
    #pragma unroll
    for (int h = 0; h < 2; ++h) {
        int slot = h * 256 + tid;
        int m = slot >> 3, col16 = slot & 7;
        short8 v = *(const short8*)&src[(size_t)m * 768 + col16 * 8];
        int key = ((m >> 3) + m) & 7;
        *(short8*)&t[m * 64 + ((col16 ^ key) * 8)] = v;
    }
    __syncthreads();
    u16* dst = bafT + ((size_t)b * 768 + dt * 64) * 1024 + mt * 64;
    #pragma unroll
    for (int h = 0; h < 2; ++h) {
        int slot = h * 256 + tid;
        int d = slot >> 3, m8 = (slot & 7) * 8;
        short8 v;
        #pragma unroll
        for (int j = 0; j < 8; ++j) {
            int m = m8 + j;
            int key = ((m >> 3) + m) & 7;
            v[j] = (short)t[m * 64 + (((d >> 3) ^ key) * 8) + (d & 7)];
        }
        *(short8*)&dst[(size_t)d * 1024 + m8] = v;
    }
}

// ---------- final GEMM (all_feat x Wcat^T) + output assembly ----------
__global__ __launch_bounds__(256) void k_gemm3(const u16* __restrict__ AF,
                                               const u16* __restrict__ BAF,
                                               const u16* __restrict__ W,
                                               const float* __restrict__ anchors,
                                               const float* __restrict__ cls_b,
                                               const float* __restrict__ reg_b,
                                               float* __restrict__ out) {
    __shared__ __attribute__((aligned(16))) u16 Al[128 * 32];
    __shared__ __attribute__((aligned(16))) u16 Bl[80 * 32];
    const int tid = threadIdx.x;
    const int tM = blockIdx.x;
    const int lane = tid & 63, w = tid >> 6;
    const int l15 = lane & 15, lk = (lane >> 4) * 8;

    f32x4 acc[2][5] = {};

    for (int ks = 0; ks < 44; ++ks) {
        const u16* Asrc = (ks < 22) ? AF : BAF;
        const int k0 = (ks < 22 ? ks : ks - 22) * 32;
        #pragma unroll
        for (int i = 0; i < 2; ++i) {
            int chunk = i * 256 + tid;
            gload16(Asrc + (size_t)(tM * 128 + (chunk >> 2)) * 768 + k0 + (chunk & 3) * 8,
                    &Al[chunk * 8]);
        }
        gload16(W + (size_t)(tid >> 2) * 1408 + ks * 32 + (tid & 3) * 8, &Bl[tid * 8]);
        if (tid < 64)
            gload16(W + (size_t)(64 + (tid >> 2)) * 1408 + ks * 32 + (tid & 3) * 8,
                    &Bl[(256 + tid) * 8]);
        __syncthreads();
        short8 af[2], bfr[5];
        #pragma unroll
        for (int m = 0; m < 2; ++m) af[m] = *(const short8*)&Al[(w * 32 + m * 16 + l15) * 32 + lk];
        #pragma unroll
        for (int n = 0; n < 5; ++n) bfr[n] = *(const short8*)&Bl[(n * 16 + l15) * 32 + lk];
        #pragma unroll
        for (int m = 0; m < 2; ++m)
            #pragma unroll
            for (int n = 0; n < 5; ++n)
                acc[m][n] = __builtin_amdgcn_mfma_f32_16x16x32_bf16(af[m], bfr[n], acc[m][n], 0, 0, 0);
        __syncthreads();
    }

    #pragma unroll
    for (int m = 0; m < 2; ++m) {
        #pragma unroll
        for (int n = 0; n < 5; ++n) {
            #pragma unroll
            for (int j = 0; j < 4; ++j) {
                int r = tM * 128 + w * 32 + m * 16 + ((lane >> 4) << 2) + j;
                int b = r >> 10, nn = r & 1023;
                if (nn < 1000) {
                    int o = n * 16 + l15;
                    float v = acc[m][n][j];
                    float* orow = out + ((size_t)b * 1000 + nn) * 77;
                    if (o < 2) {
                        orow[o] = v + cls_b[o];
                    } else if (o < 75) {
                        int jj = o - 2;
                        orow[4 + jj] = v + reg_b[jj] + anchors[nn * 77 + 4 + jj];
                        if (o == 2) orow[2] = anchors[nn * 77 + 2];
                        if (o == 3) orow[3] = anchors[nn * 77 + 3];
                    }
                }
            }
        }
    }
}

extern "C" void kernel_launch(void* const* d_in, const int* in_sizes, int n_in,
                              void* d_out, int out_size, void* d_ws, size_t ws_size,
                              hipStream_t stream) {
    const float* x       = (const float*)d_in[0];
    const float* anchors = (const float*)d_in[1];
    const float* conv1_w = (const float*)d_in[2];
    const float* conv1_b = (const float*)d_in[3];
    const float* attn_w  = (const float*)d_in[4];
    const float* attn_b  = (const float*)d_in[5];
    const float* cls_w   = (const float*)d_in[6];
    const float* cls_b   = (const float*)d_in[7];
    const float* reg_w   = (const float*)d_in[8];
    const float* reg_b   = (const float*)d_in[9];
    const int*   cut_xs  = (const int*)d_in[12];
    const void*  invalid = d_in[13];
    float* out = (float*)d_out;

    char* ws = (char*)d_ws;
    float* feat    = (float*)(ws + 0);
    int*   xn      = (int*)  (ws + 1802240);
    int*   mflag   = xn + 11004;
    u16*   attn_wb = (u16*)  (ws + 1846272);
    u16*   wcat    = (u16*)  (ws + 3288064);
    u16*   baf     = (u16*)  (ws + 3513344);
    u16*   bafT    = (u16*)  (ws + 53844992);
    u16*   att     = (u16*)  (ws + 104176640);
    u16*   att_feat= (u16*)  (ws + 171285504);

    k_prep_attnw<<<2816, 256, 0, stream>>>(attn_w, attn_wb);
    k_prep_wcat<<<440, 256, 0, stream>>>(cls_w, reg_w, wcat);
    k_detect_mask<<<1, 256, 0, stream>>>((const unsigned char*)invalid, mflag);
    k_prep_xn<<<43, 256, 0, stream>>>(cut_xs, invalid, mflag, xn);
    k_conv<<<dim3(32, 16), 256, 0, stream>>>(x, conv1_w, conv1_b, feat);
    k_gather<<<dim3(256, 32), 384, 0, stream>>>(feat, xn, baf);
    // GEMM1: att = baf(32768x704) * attn_wb(1024x704)^T ; 128x4 tiles of 256
    k_gemm256<<<512, 512, 0, stream>>>(baf, 0L, 768, attn_wb, 0L, 704,
                                       att, 0L, 1024, 4, 512, 512, 22);
    k_softmax<<<32768, 128, 0, stream>>>(att, attn_b);
    k_transpose<<<dim3(192, 32), 256, 0, stream>>>(baf, bafT);
    // GEMM2 (batched over 32): att_feat = att(1024x1024) * bafT(768x1024)^T ; 4x3 tiles
    k_gemm256<<<384, 512, 0, stream>>>(att, (long)1024 * 1024, 1024,
                                       bafT, (long)768 * 1024, 1024,
                                       att_feat, (long)1024 * 768, 768, 3, 12, 384, 32);
    k_gemm3<<<256, 256, 0, stream>>>(att_feat, baf, wcat, anchors, cls_b, reg_b, out);
}

// Round 4
// 385.462 us; speedup vs baseline: 1.0618x; 1.0618x over previous
//
#include <hip/hip_runtime.h>

// LaneATT head, MI355X. Pipeline:
//  prep -> conv1x1 -> gather(baf bf16 [B][1024][768]) -> GEMM1 (ring-3 counted-vmcnt) ->
//  softmax+shift -> transpose -> GEMM2 (ring-3, batched) -> GEMM3 (ring-3) + epilogue.
// ws layout unchanged (total 221,617,152 bytes).

typedef unsigned short u16;
typedef short short8 __attribute__((ext_vector_type(8)));
typedef float f32x4 __attribute__((ext_vector_type(4)));

__device__ __forceinline__ u16 f2bf(float f) {
    union { float f; unsigned u; } v; v.f = f;
    unsigned r = v.u + 0x7FFFu + ((v.u >> 16) & 1u);
    return (u16)(r >> 16);
}
__device__ __forceinline__ float bf2f(u16 u) {
    union { unsigned u; float f; } v; v.u = ((unsigned)u) << 16;
    return v.f;
}

// async global->LDS, 16B per lane; lds dest = wave-uniform base + lane*16B (linear).
__device__ __forceinline__ void gload16(const u16* gsrc, u16* ldst) {
    __builtin_amdgcn_global_load_lds(
        (const __attribute__((address_space(1))) unsigned int*)gsrc,
        (__attribute__((address_space(3))) unsigned int*)ldst, 16, 0, 0);
}

// ---------- prep kernels ----------

__global__ __launch_bounds__(256) void k_prep_attnw(const float* __restrict__ attn_w,
                                                    u16* __restrict__ attn_wb) {
    int i = blockIdx.x * 256 + threadIdx.x;          // over 1024*704
    if (i >= 1024 * 704) return;
    int r = i / 704;
    attn_wb[i] = (r < 999) ? f2bf(attn_w[i]) : (u16)0;
}

__global__ __launch_bounds__(256) void k_prep_wcat(const float* __restrict__ cls_w,
                                                   const float* __restrict__ reg_w,
                                                   u16* __restrict__ wcat) {
    int i = blockIdx.x * 256 + threadIdx.x;          // over 80*1408
    if (i >= 80 * 1408) return;
    int o = i / 1408, k = i - o * 1408;
    float v = 0.f;
    if (o < 2) v = cls_w[o * 1408 + k];
    else if (o < 75) v = reg_w[(o - 2) * 1408 + k];
    wcat[i] = f2bf(v);
}

__global__ __launch_bounds__(256) void k_detect_mask(const unsigned char* __restrict__ mask,
                                                     int* __restrict__ flag) {
    int any = 0;
    for (int i = threadIdx.x; i < 11000; i += 256)
        if ((i & 3) && mask[i]) any = 1;
    any = __any(any) ? 1 : 0;
    __shared__ int sh[4];
    if ((threadIdx.x & 63) == 0) sh[threadIdx.x >> 6] = any;
    __syncthreads();
    if (threadIdx.x == 0) *flag = sh[0] | sh[1] | sh[2] | sh[3];
}

__global__ __launch_bounds__(256) void k_prep_xn(const int* __restrict__ cut_xs,
                                                 const void* __restrict__ mask,
                                                 const int* __restrict__ flag,
                                                 int* __restrict__ xn) {
    int i = blockIdx.x * 256 + threadIdx.x;          // over 11000 = (n,y)
    if (i >= 11000) return;
    int inv = (*flag) ? (int)((const unsigned char*)mask)[i]
                      : ((const int*)mask)[i];
    int n = i / 11, y = i - n * 11;
    xn[i] = inv ? -1 : cut_xs[n * 704 + y];
}

// ---------- conv 1x1 ----------
__global__ __launch_bounds__(256) void k_conv(const float* __restrict__ x,
                                              const float* __restrict__ w1,
                                              const float* __restrict__ b1,
                                              float* __restrict__ feat) {
    __shared__ float wl[4][512];
    const int b = blockIdx.x, og = blockIdx.y;
    for (int i = threadIdx.x; i < 4 * 512; i += 256)
        wl[i >> 9][i & 511] = w1[(og * 4 + (i >> 9)) * 512 + (i & 511)];
    __syncthreads();
    const int p = threadIdx.x;
    if (p >= 220) return;
    const float* xb = x + (size_t)b * 512 * 220 + p;
    float a0 = 0.f, a1 = 0.f, a2 = 0.f, a3 = 0.f;
    #pragma unroll 4
    for (int c = 0; c < 512; ++c) {
        float xv = xb[(size_t)c * 220];
        a0 = fmaf(xv, wl[0][c], a0);
        a1 = fmaf(xv, wl[1][c], a1);
        a2 = fmaf(xv, wl[2][c], a2);
        a3 = fmaf(xv, wl[3][c], a3);
    }
    float* fo = feat + (size_t)b * 14080 + (og * 4) * 220 + p;
    fo[0]   = a0 + b1[og * 4 + 0];
    fo[220] = a1 + b1[og * 4 + 1];
    fo[440] = a2 + b1[og * 4 + 2];
    fo[660] = a3 + b1[og * 4 + 3];
}

// ---------- gather -> baf (bf16, [B][1024][768], pads zeroed), short8 stores ----------
__global__ __launch_bounds__(384) void k_gather(const float* __restrict__ feat,
                                                const int* __restrict__ xn,
                                                u16* __restrict__ baf) {
    const int b = blockIdx.y, t = threadIdx.x;
    const int a = t / 96, r = t - a * 96;
    const int n = blockIdx.x * 4 + a;
    const int d8 = r * 8;
    const float* fb = feat + (size_t)b * 14080;
    short8 o = {0, 0, 0, 0, 0, 0, 0, 0};
    #pragma unroll
    for (int j = 0; j < 8; ++j) {
        int d = d8 + j;
        float v = 0.f;
        if (n < 1000 && d < 704) {
            int c = d / 11, y = d - c * 11;
            int xv = xn[n * 11 + y];
            if (xv >= 0) v = fb[c * 220 + y * 20 + xv];
        }
        o[j] = (short)f2bf(v);
    }
    *(short8*)&baf[((size_t)b * 1024 + n) * 768 + d8] = o;
}

// ---------- 256x256-tile bf16 GEMM, ring-3 counted-vmcnt pipeline ----------
// C = A(MxK) * Bt(NrowsxK)^T, row-major bf16; 512 threads = 8 waves (2x4).
// BK=32. LDS: 3 ring buffers x (A 16KB + B 16KB) = 96KB, 1 block/CU.
// Per iter t: STAGE(t+2) -> vmcnt(8) [t+1,t+2 in flight, t landed] -> barrier ->
// ds_read(swz)+32 MFMA -> barrier. LDS swizzle: 16B slot ^= (row>>1)&3 (2-way).
__global__ __launch_bounds__(512, 2) void k_gemm256(const u16* __restrict__ A, long sAb, int lda,
                                                    const u16* __restrict__ Bt, long sBb, int ldb,
                                                    u16* __restrict__ C, long sCb, int ldc,
                                                    int ntN, int tilesPerBatch, int nwg, int ksteps) {
    __shared__ __attribute__((aligned(16))) u16 Al[3][8192];
    __shared__ __attribute__((aligned(16))) u16 Bl[3][8192];
    const int bid = blockIdx.x;
    const int cpx = nwg >> 3;                        // bijective XCD swizzle (nwg%8==0)
    const int logical = (bid & 7) * cpx + (bid >> 3);
    const int batch = logical / tilesPerBatch;
    const int t0 = logical - batch * tilesPerBatch;
    const int tM = t0 / ntN, tN = t0 - tM * ntN;
    A  += (size_t)batch * sAb;
    Bt += (size_t)batch * sBb;
    C  += (size_t)batch * sCb;

    const int tid = threadIdx.x;
    const int lane = tid & 63, w = tid >> 6;
    const int wr = w >> 2, wc = w & 3;               // wave tile: rows wr*128, cols wc*64
    const int l15 = lane & 15;
    const int lkswz = (((lane >> 4) ^ ((lane >> 1) & 3)) * 8);  // swizzled k-slot (u16 units)
    const u16* Abase = A + (size_t)tM * 256 * lda;
    const u16* Bbase = Bt + (size_t)tN * 256 * ldb;
    // staging: per issue 512thr x 16B = 128 rows; phys slot tid&3 holds logical
    // slot (tid&3)^skey, skey=(row>>1)&3=(tid>>3)&3
    const int srow = tid >> 2;
    const int sgcol = (((tid & 3) ^ ((tid >> 3) & 3)) * 8);

    f32x4 acc[8][4] = {};

    auto STAGE = [&](int kt) {
        const int bi = kt % 3;
        const int k0 = kt * 32;
        #pragma unroll
        for (int j = 0; j < 2; ++j)
            gload16(Abase + (size_t)(j * 128 + srow) * lda + k0 + sgcol,
                    &Al[bi][j * 4096 + tid * 8]);
        #pragma unroll
        for (int j = 0; j < 2; ++j)
            gload16(Bbase + (size_t)(j * 128 + srow) * ldb + k0 + sgcol,
                    &Bl[bi][j * 4096 + tid * 8]);
    };
    auto COMPUTE = [&](int kt) {
        const u16* __restrict__ Ab = Al[kt % 3];
        const u16* __restrict__ Bb = Bl[kt % 3];
        short8 af[8], bv[4];
        #pragma unroll
        for (int m = 0; m < 8; ++m)
            af[m] = *(const short8*)&Ab[(wr * 128 + m * 16 + l15) * 32 + lkswz];
        #pragma unroll
        for (int n = 0; n < 4; ++n)
            bv[n] = *(const short8*)&Bb[(wc * 64 + n * 16 + l15) * 32 + lkswz];
        __builtin_amdgcn_s_setprio(1);
        #pragma unroll
        for (int m = 0; m < 8; ++m)
            #pragma unroll
            for (int n = 0; n < 4; ++n)
                acc[m][n] = __builtin_amdgcn_mfma_f32_16x16x32_bf16(af[m], bv[n], acc[m][n], 0, 0, 0);
        __builtin_amdgcn_s_setprio(0);
    };

    STAGE(0);
    STAGE(1);
    for (int t = 0; t < ksteps; ++t) {
        if (t + 2 < ksteps) {
            STAGE(t + 2);
            asm volatile("s_waitcnt vmcnt(8)" ::: "memory");
        } else if (t + 1 < ksteps) {
            asm volatile("s_waitcnt vmcnt(4)" ::: "memory");
        } else {
            asm volatile("s_waitcnt vmcnt(0)" ::: "memory");
        }
        __builtin_amdgcn_s_barrier();
        asm volatile("" ::: "memory");
        COMPUTE(t);
        asm volatile("" ::: "memory");
        __builtin_amdgcn_s_barrier();
    }

    const int rb = tM * 256 + wr * 128 + ((lane >> 4) << 2);
    const int cb = tN * 256 + wc * 64 + l15;
    #pragma unroll
    for (int m = 0; m < 8; ++m)
        #pragma unroll
        for (int n = 0; n < 4; ++n)
            #pragma unroll
            for (int j = 0; j < 4; ++j)
                C[(size_t)(rb + m * 16 + j) * ldc + cb + n * 16] = f2bf(acc[m][n][j]);
}

// ---------- softmax + diagonal-shift, 1 row per 128-thread block, short8 ----------
__global__ __launch_bounds__(128) void k_softmax(u16* __restrict__ att,
                                                 const float* __restrict__ attn_b) {
    __shared__ float sv[1000];
    __shared__ float red[2], red2[2];
    const int row = blockIdx.x;
    const int n = row & 1023;
    u16* __restrict__ r = att + (size_t)row * 1024;
    const int tid = threadIdx.x, c8 = tid * 8;
    if (n >= 1000) {
        short8 z = {0, 0, 0, 0, 0, 0, 0, 0};
        *(short8*)&r[c8] = z;
        return;
    }
    short8 v = *(const short8*)&r[c8];
    float f[8];
    float lmax = -1e30f;
    #pragma unroll
    for (int j = 0; j < 8; ++j) {
        int c = c8 + j;
        f[j] = (c < 999) ? bf2f((u16)v[j]) + attn_b[c] : -1e30f;
        lmax = fmaxf(lmax, f[j]);
    }
    #pragma unroll
    for (int o = 32; o > 0; o >>= 1) lmax = fmaxf(lmax, __shfl_xor(lmax, o));
    if ((tid & 63) == 0) red[tid >> 6] = lmax;
    __syncthreads();
    float gmax = fmaxf(red[0], red[1]);
    float lsum = 0.f;
    #pragma unroll
    for (int j = 0; j < 8; ++j) {
        int c = c8 + j;
        float e = (c < 999) ? __expf(f[j] - gmax) : 0.f;
        if (c < 999) sv[c] = e;
        lsum += e;
    }
    #pragma unroll
    for (int o = 32; o > 0; o >>= 1) lsum += __shfl_xor(lsum, o);
    if ((tid & 63) == 0) red2[tid >> 6] = lsum;
    __syncthreads();
    float inv = 1.f / (red2[0] + red2[1]);
    short8 o;
    #pragma unroll
    for (int j = 0; j < 8; ++j) {
        int c = c8 + j;
        float val = 0.f;
        if (c < 1000 && c != n) val = sv[c - (c > n ? 1 : 0)] * inv;
        o[j] = (short)f2bf(val);
    }
    *(short8*)&r[c8] = o;
}

// ---------- baf transpose: bafT[b][d][m] = baf[b][m][d], xor-swizzled LDS ----------
__global__ __launch_bounds__(256) void k_transpose(const u16* __restrict__ baf,
                                                   u16* __restrict__ bafT) {
    __shared__ __attribute__((aligned(16))) u16 t[64 * 64];
    const int mt = blockIdx.x & 15, dt = blockIdx.x >> 4;
    const int b = blockIdx.y;
    const int tid = threadIdx.x;
    const u16* src = baf + ((size_t)b * 1024 + mt * 64) * 768 + dt * 64;
    #pragma unroll
    for (int h = 0; h < 2; ++h) {
        int slot = h * 256 + tid;
        int m = slot >> 3, col16 = slot & 7;
        short8 v = *(const short8*)&src[(size_t)m * 768 + col16 * 8];
        int key = ((m >> 3) + m) & 7;
        *(short8*)&t[m * 64 + ((col16 ^ key) * 8)] = v;
    }
    __syncthreads();
    u16* dst = bafT + ((size_t)b * 768 + dt * 64) * 1024 + mt * 64;
    #pragma unroll
    for (int h = 0; h < 2; ++h) {
        int slot = h * 256 + tid;
        int d = slot >> 3, m8 = (slot & 7) * 8;
        short8 v;
        #pragma unroll
        for (int j = 0; j < 8; ++j) {
            int m = m8 + j;
            int key = ((m >> 3) + m) & 7;
            v[j] = (short)t[m * 64 + (((d >> 3) ^ key) * 8) + (d & 7)];
        }
        *(short8*)&dst[(size_t)d * 1024 + m8] = v;
    }
}

// ---------- final GEMM (all_feat x Wcat^T), ring-3 pipeline + output assembly ----------
// 256 threads, 128x80 tile, K=1408 (44 steps: 22 from AF, 22 from BAF).
__global__ __launch_bounds__(256) void k_gemm3(const u16* __restrict__ AF,
                                               const u16* __restrict__ BAF,
                                               const u16* __restrict__ W,
                                               const float* __restrict__ anchors,
                                               const float* __restrict__ cls_b,
                                               const float* __restrict__ reg_b,
                                               float* __restrict__ out) {
    __shared__ __attribute__((aligned(16))) u16 Aq[3][4096];  // 128x32
    __shared__ __attribute__((aligned(16))) u16 Bq[3][4096];  // 128x32 (rows>=80 unused)
    const int tid = threadIdx.x;
    const int tM = blockIdx.x;
    const int lane = tid & 63, w = tid >> 6;
    const int l15 = lane & 15;
    const int lkswz = (((lane >> 4) ^ ((lane >> 1) & 3)) * 8);
    const int srow = tid >> 2;                        // 0..63 per issue
    const int sgcol = (((tid & 3) ^ ((tid >> 3) & 3)) * 8);

    f32x4 acc[2][5] = {};

    auto STAGE = [&](int kt) {
        const int bi = kt % 3;
        const u16* Asrc = (kt < 22) ? AF : BAF;
        const int k0 = (kt < 22 ? kt : kt - 22) * 32;
        #pragma unroll
        for (int j = 0; j < 2; ++j)
            gload16(Asrc + (size_t)(tM * 128 + j * 64 + srow) * 768 + k0 + sgcol,
                    &Aq[bi][j * 2048 + tid * 8]);
        #pragma unroll
        for (int j = 0; j < 2; ++j)
            gload16(W + (size_t)(j * 64 + srow) * 1408 + kt * 32 + sgcol,
                    &Bq[bi][j * 2048 + tid * 8]);
    };
    auto COMPUTE = [&](int kt) {
        const u16* __restrict__ Ab = Aq[kt % 3];
        const u16* __restrict__ Bb = Bq[kt % 3];
        short8 af[2], bv[5];
        #pragma unroll
        for (int m = 0; m < 2; ++m)
            af[m] = *(const short8*)&Ab[(w * 32 + m * 16 + l15) * 32 + lkswz];
        #pragma unroll
        for (int n = 0; n < 5; ++n)
            bv[n] = *(const short8*)&Bb[(n * 16 + l15) * 32 + lkswz];
        __builtin_amdgcn_s_setprio(1);
        #pragma unroll
        for (int m = 0; m < 2; ++m)
            #pragma unroll
            for (int n = 0; n < 5; ++n)
                acc[m][n] = __builtin_amdgcn_mfma_f32_16x16x32_bf16(af[m], bv[n], acc[m][n], 0, 0, 0);
        __builtin_amdgcn_s_setprio(0);
    };

    STAGE(0);
    STAGE(1);
    for (int t = 0; t < 44; ++t) {
        if (t + 2 < 44) {
            STAGE(t + 2);
            asm volatile("s_waitcnt vmcnt(8)" ::: "memory");
        } else if (t + 1 < 44) {
            asm volatile("s_waitcnt vmcnt(4)" ::: "memory");
        } else {
            asm volatile("s_waitcnt vmcnt(0)" ::: "memory");
        }
        __builtin_amdgcn_s_barrier();
        asm volatile("" ::: "memory");
        COMPUTE(t);
        asm volatile("" ::: "memory");
        __builtin_amdgcn_s_barrier();
    }

    #pragma unroll
    for (int m = 0; m < 2; ++m) {
        #pragma unroll
        for (int n = 0; n < 5; ++n) {
            #pragma unroll
            for (int j = 0; j < 4; ++j) {
                int r = tM * 128 + w * 32 + m * 16 + ((lane >> 4) << 2) + j;
                int b = r >> 10, nn = r & 1023;
                if (nn < 1000) {
                    int o = n * 16 + l15;
                    float v = acc[m][n][j];
                    float* orow = out + ((size_t)b * 1000 + nn) * 77;
                    if (o < 2) {
                        orow[o] = v + cls_b[o];
                    } else if (o < 75) {
                        int jj = o - 2;
                        orow[4 + jj] = v + reg_b[jj] + anchors[nn * 77 + 4 + jj];
                        if (o == 2) orow[2] = anchors[nn * 77 + 2];
                        if (o == 3) orow[3] = anchors[nn * 77 + 3];
                    }
                }
            }
        }
    }
}

extern "C" void kernel_launch(void* const* d_in, const int* in_sizes, int n_in,
                              void* d_out, int out_size, void* d_ws, size_t ws_size,
                              hipStream_t stream) {
    const float* x       = (const float*)d_in[0];
    const float* anchors = (const float*)d_in[1];
    const float* conv1_w = (const float*)d_in[2];
    const float* conv1_b = (const float*)d_in[3];
    const float* attn_w  = (const float*)d_in[4];
    const float* attn_b  = (const float*)d_in[5];
    const float* cls_w   = (const float*)d_in[6];
    const float* cls_b   = (const float*)d_in[7];
    const float* reg_w   = (const float*)d_in[8];
    const float* reg_b   = (const float*)d_in[9];
    const int*   cut_xs  = (const int*)d_in[12];
    const void*  invalid = d_in[13];
    float* out = (float*)d_out;

    char* ws = (char*)d_ws;
    float* feat    = (float*)(ws + 0);
    int*   xn      = (int*)  (ws + 1802240);
    int*   mflag   = xn + 11004;
    u16*   attn_wb = (u16*)  (ws + 1846272);
    u16*   wcat    = (u16*)  (ws + 3288064);
    u16*   baf     = (u16*)  (ws + 3513344);
    u16*   bafT    = (u16*)  (ws + 53844992);
    u16*   att     = (u16*)  (ws + 104176640);
    u16*   att_feat= (u16*)  (ws + 171285504);

    k_prep_attnw<<<2816, 256, 0, stream>>>(attn_w, attn_wb);
    k_prep_wcat<<<440, 256, 0, stream>>>(cls_w, reg_w, wcat);
    k_detect_mask<<<1, 256, 0, stream>>>((const unsigned char*)invalid, mflag);
    k_prep_xn<<<43, 256, 0, stream>>>(cut_xs, invalid, mflag, xn);
    k_conv<<<dim3(32, 16), 256, 0, stream>>>(x, conv1_w, conv1_b, feat);
    k_gather<<<dim3(256, 32), 384, 0, stream>>>(feat, xn, baf);
    // GEMM1: att = baf(32768x704) * attn_wb(1024x704)^T ; 128x4 tiles of 256
    k_gemm256<<<512, 512, 0, stream>>>(baf, 0L, 768, attn_wb, 0L, 704,
                                       att, 0L, 1024, 4, 512, 512, 22);
    k_softmax<<<32768, 128, 0, stream>>>(att, attn_b);
    k_transpose<<<dim3(192, 32), 256, 0, stream>>>(baf, bafT);
    // GEMM2 (batched over 32): att_feat = att(1024x1024) * bafT(768x1024)^T ; 4x3 tiles
    k_gemm256<<<384, 512, 0, stream>>>(att, (long)1024 * 1024, 1024,
                                       bafT, (long)768 * 1024, 1024,
                                       att_feat, (long)1024 * 768, 768, 3, 12, 384, 32);
    k_gemm3<<<256, 256, 0, stream>>>(att_feat, baf, wcat, anchors, cls_b, reg_b, out);
}

// Round 6
// 383.808 us; speedup vs baseline: 1.0664x; 1.0043x over previous
//
#include <hip/hip_runtime.h>

// LaneATT head, MI355X.
// all_feat[b][1024][1536] bf16: cols 0:768 = att_feat (GEMM2 C), 768:1536 = baf (gather).
// wcat is 256x1536 laid out to MATCH af geometry (k 704..767 and 1472..1535 zero).
// Pipeline: prep -> conv -> gather(all_feat hi) -> G1=k_g8(af_hi x attn_wb^T -> att)
//  -> softmax(att) -> transpose(af_hi -> bafT) -> G2=k_g8(att x bafT^T -> af_lo)
//  -> G3=k_g8(af x wcat^T -> c3f f32, K=1536) -> k_out epilogue.
// ws layout (bytes): wcat @0 (786,432) | attn_wb @786,432 (1,441,792)
//  | af @2,228,224 (100,663,296) | bafT @102,891,520 (50,331,648; c3f f32 reuses base)
//  | att @153,223,168 (67,108,864; feat f32 @153,223,168 + xn @155,025,408 live pre-GEMM1).
//  End 220,332,032.

typedef unsigned short u16;
typedef short short8 __attribute__((ext_vector_type(8)));
typedef float f32x4 __attribute__((ext_vector_type(4)));

__device__ __forceinline__ u16 f2bf(float f) {
    union { float f; unsigned u; } v; v.f = f;
    unsigned r = v.u + 0x7FFFu + ((v.u >> 16) & 1u);
    return (u16)(r >> 16);
}
__device__ __forceinline__ float bf2f(u16 u) {
    union { unsigned u; float f; } v; v.u = ((unsigned)u) << 16;
    return v.f;
}

__device__ __forceinline__ void gload16(const u16* gsrc, u16* ldst) {
    __builtin_amdgcn_global_load_lds(
        (const __attribute__((address_space(1))) unsigned int*)gsrc,
        (__attribute__((address_space(3))) unsigned int*)ldst, 16, 0, 0);
}

// inline-asm LDS read, 16B; addr = 32-bit LDS byte offset (low bits of flat addr)
#define DSR(d, a, off) asm volatile("ds_read_b128 %0, %1 offset:" #off : "=v"(d) : "v"(a))
#define LGKM0 do { asm volatile("s_waitcnt lgkmcnt(0)" ::: "memory"); \
                   __builtin_amdgcn_sched_barrier(0); } while (0)
#define WVM(n) asm volatile("s_waitcnt vmcnt(" #n ")" ::: "memory")
#define BAR __builtin_amdgcn_s_barrier()

#define MFCL(Aarr, Barr, MH) do { \
    __builtin_amdgcn_s_setprio(1); \
    _Pragma("unroll") \
    for (int m = 0; m < 4; ++m) { \
        _Pragma("unroll") \
        for (int n = 0; n < 4; ++n) \
            acc[(MH) * 4 + m][n] = __builtin_amdgcn_mfma_f32_16x16x32_bf16( \
                Aarr[m], Barr[n], acc[(MH) * 4 + m][n], 0, 0, 0); \
    } \
    __builtin_amdgcn_s_setprio(0); } while (0)

// ---------- prep ----------

__global__ __launch_bounds__(256) void k_prep_attnw(const float* __restrict__ attn_w,
                                                    u16* __restrict__ attn_wb) {
    int i = blockIdx.x * 256 + threadIdx.x;          // 1024*704
    if (i >= 1024 * 704) return;
    int r = i / 704;
    attn_wb[i] = (r < 999) ? f2bf(attn_w[i]) : (u16)0;
}

// wcat[o][k], 256x1536, matching af geometry: k<704 -> w[k]; 768<=k<1472 -> w[k-64]; else 0
__global__ __launch_bounds__(256) void k_prep_wcat(const float* __restrict__ cls_w,
                                                   const float* __restrict__ reg_w,
                                                   u16* __restrict__ wcat) {
    int i = blockIdx.x * 256 + threadIdx.x;          // 256*1536
    if (i >= 256 * 1536) return;
    int o = i / 1536, k = i - o * 1536;
    int ksrc = -1;
    if (k < 704) ksrc = k;
    else if (k >= 768 && k < 1472) ksrc = k - 64;
    float v = 0.f;
    if (ksrc >= 0) {
        if (o < 2) v = cls_w[o * 1408 + ksrc];
        else if (o < 75) v = reg_w[(o - 2) * 1408 + ksrc];
    }
    wcat[i] = f2bf(v);
}

__global__ __launch_bounds__(256) void k_detect_mask(const unsigned char* __restrict__ mask,
                                                     int* __restrict__ flag) {
    int any = 0;
    for (int i = threadIdx.x; i < 11000; i += 256)
        if ((i & 3) && mask[i]) any = 1;
    any = __any(any) ? 1 : 0;
    __shared__ int sh[4];
    if ((threadIdx.x & 63) == 0) sh[threadIdx.x >> 6] = any;
    __syncthreads();
    if (threadIdx.x == 0) *flag = sh[0] | sh[1] | sh[2] | sh[3];
}

__global__ __launch_bounds__(256) void k_prep_xn(const int* __restrict__ cut_xs,
                                                 const void* __restrict__ mask,
                                                 const int* __restrict__ flag,
                                                 int* __restrict__ xn) {
    int i = blockIdx.x * 256 + threadIdx.x;          // 11000
    if (i >= 11000) return;
    int inv = (*flag) ? (int)((const unsigned char*)mask)[i]
                      : ((const int*)mask)[i];
    int n = i / 11, y = i - n * 11;
    xn[i] = inv ? -1 : cut_xs[n * 704 + y];
}

// ---------- conv 1x1 ----------
__global__ __launch_bounds__(256) void k_conv(const float* __restrict__ x,
                                              const float* __restrict__ w1,
                                              const float* __restrict__ b1,
                                              float* __restrict__ feat) {
    __shared__ float wl[4][512];
    const int b = blockIdx.x, og = blockIdx.y;
    for (int i = threadIdx.x; i < 4 * 512; i += 256)
        wl[i >> 9][i & 511] = w1[(og * 4 + (i >> 9)) * 512 + (i & 511)];
    __syncthreads();
    const int p = threadIdx.x;
    if (p >= 220) return;
    const float* xb = x + (size_t)b * 512 * 220 + p;
    float a0 = 0.f, a1 = 0.f, a2 = 0.f, a3 = 0.f;
    #pragma unroll 4
    for (int c = 0; c < 512; ++c) {
        float xv = xb[(size_t)c * 220];
        a0 = fmaf(xv, wl[0][c], a0);
        a1 = fmaf(xv, wl[1][c], a1);
        a2 = fmaf(xv, wl[2][c], a2);
        a3 = fmaf(xv, wl[3][c], a3);
    }
    float* fo = feat + (size_t)b * 14080 + (og * 4) * 220 + p;
    fo[0]   = a0 + b1[og * 4 + 0];
    fo[220] = a1 + b1[og * 4 + 1];
    fo[440] = a2 + b1[og * 4 + 2];
    fo[660] = a3 + b1[og * 4 + 3];
}

// ---------- gather -> all_feat upper half ----------
__global__ __launch_bounds__(384) void k_gather(const float* __restrict__ feat,
                                                const int* __restrict__ xn,
                                                u16* __restrict__ af) {
    const int b = blockIdx.y, t = threadIdx.x;
    const int a = t / 96, r = t - a * 96;
    const int n = blockIdx.x * 4 + a;
    const int d8 = r * 8;
    const float* fb = feat + (size_t)b * 14080;
    short8 o = {0, 0, 0, 0, 0, 0, 0, 0};
    #pragma unroll
    for (int j = 0; j < 8; ++j) {
        int d = d8 + j;
        float v = 0.f;
        if (n < 1000 && d < 704) {
            int c = d / 11, y = d - c * 11;
            int xv = xn[n * 11 + y];
            if (xv >= 0) v = fb[c * 220 + y * 20 + xv];
        }
        o[j] = (short)f2bf(v);
    }
    *(short8*)&af[((size_t)b * 1024 + n) * 1536 + 768 + d8] = o;
}

// ---------- 8-phase 256x256 bf16 GEMM engine ----------
// C = A(MxK) x Bt(NrowsxK)^T. BK=64 (2 k-halves of 32), 2 LDS buffers, 512 thr.
// Per K-tile: 4 phases {stage 1 half | asm ds_read subtile | lgkm0 | 16 MFMA | barrier},
// one vmcnt(4) per tile (never 0 in steady state). LDS 16B-slot swizzle ^(row>>1)&3.
__global__ __launch_bounds__(512, 2) void k_g8(const u16* __restrict__ A, long sAb, int lda,
                                               const u16* __restrict__ Bt, long sBb, int ldb,
                                               void* __restrict__ Cv, long sCb, int ldc,
                                               int ntN, int tpb, int nwg, int ks, int cf32) {
    __shared__ __attribute__((aligned(16))) u16 LDS[65536];   // 128 KB
    // A(buf,kh) u16-base = (buf*2+kh)*8192 ; B(buf,kh) = 32768 + (buf*2+kh)*8192
    const int bid = blockIdx.x;
    const int cpx = nwg >> 3;                         // bijective XCD swizzle (nwg%8==0)
    const int logical = (bid & 7) * cpx + (bid >> 3);
    const int batch = logical / tpb;
    const int t0 = logical - batch * tpb;
    const int tM = t0 / ntN, tN = t0 - tM * ntN;
    A  += (size_t)batch * sAb;
    Bt += (size_t)batch * sBb;

    const int tid = threadIdx.x;
    const int lane = tid & 63, w = tid >> 6;
    const int wr = w >> 2, wc = w & 3;                // wave tile rows wr*128, cols wc*64
    const int l15 = lane & 15;
    const int lkswz = ((lane >> 4) ^ ((l15 >> 1) & 3)) * 8;   // swizzled k-slot (u16)
    const u16* Abase = A + (size_t)tM * 256 * lda;
    const u16* Bbase = Bt + (size_t)tN * 256 * ldb;
    const int srow = tid >> 2;
    const int sgc = (((tid & 3) ^ ((tid >> 3) & 3)) * 8);     // inverse-swizzled global col

    f32x4 acc[8][4] = {};

    auto SGA = [&](int t, int kh) {
        const int base = ((t & 1) * 2 + kh) * 8192;
        const u16* g = Abase + (size_t)srow * lda + t * 64 + kh * 32 + sgc;
        gload16(g, &LDS[base + tid * 8]);
        gload16(g + (size_t)128 * lda, &LDS[base + 4096 + tid * 8]);
    };
    auto SGB = [&](int t, int kh) {
        const int base = 32768 + ((t & 1) * 2 + kh) * 8192;
        const u16* g = Bbase + (size_t)srow * ldb + t * 64 + kh * 32 + sgc;
        gload16(g, &LDS[base + tid * 8]);
        gload16(g + (size_t)128 * ldb, &LDS[base + 4096 + tid * 8]);
    };

    // prologue: tile0 fully + tile1 k0; wait tile0 (4 loads of tile1 stay in flight)
    SGA(0, 0); SGB(0, 0); SGA(0, 1); SGB(0, 1);
    if (ks > 1) { SGA(1, 0); SGB(1, 0); WVM(4); } else { WVM(0); }
    BAR;

    const unsigned aAl = (unsigned)(size_t)&LDS[(wr * 128 + l15) * 32 + lkswz];
    const unsigned aBl = (unsigned)(size_t)&LDS[32768 + (wc * 64 + l15) * 32 + lkswz];

    for (int t = 0; t < ks; ++t) {
        const int c = t & 1;
        const unsigned bo = (unsigned)(c * 2) * 16384u;       // buffer byte offset
        short8 av[4], bk[4];
        // ph1: kh0, mh0  | stage (t+1).A.k1
        if (t + 1 < ks) SGA(t + 1, 1);
        {
            unsigned aA = aAl + bo, aB = aBl + bo;
            DSR(bk[0], aB, 0); DSR(bk[1], aB, 1024); DSR(bk[2], aB, 2048); DSR(bk[3], aB, 3072);
            DSR(av[0], aA, 0); DSR(av[1], aA, 1024); DSR(av[2], aA, 2048); DSR(av[3], aA, 3072);
            LGKM0;
            MFCL(av, bk, 0);
        }
        BAR;
        // ph2: kh0, mh1  | stage (t+1).B.k1
        if (t + 1 < ks) SGB(t + 1, 1);
        {
            unsigned aA = aAl + bo;
            DSR(av[0], aA, 4096); DSR(av[1], aA, 5120); DSR(av[2], aA, 6144); DSR(av[3], aA, 7168);
            LGKM0;
            MFCL(av, bk, 1);
        }
        BAR;
        // ph3: kh1, mh0  | stage (t+2).A.k0
        if (t + 2 < ks) SGA(t + 2, 0);
        {
            unsigned aA = aAl + bo + 16384u, aB = aBl + bo + 16384u;
            DSR(bk[0], aB, 0); DSR(bk[1], aB, 1024); DSR(bk[2], aB, 2048); DSR(bk[3], aB, 3072);
            DSR(av[0], aA, 0); DSR(av[1], aA, 1024); DSR(av[2], aA, 2048); DSR(av[3], aA, 3072);
            LGKM0;
            MFCL(av, bk, 0);
        }
        BAR;
        // ph4: kh1, mh1  | stage (t+2).B.k0 ; per-tile counted vmcnt
        if (t + 2 < ks) SGB(t + 2, 0);
        {
            unsigned aA = aAl + bo + 16384u;
            DSR(av[0], aA, 4096); DSR(av[1], aA, 5120); DSR(av[2], aA, 6144); DSR(av[3], aA, 7168);
            LGKM0;
            MFCL(av, bk, 1);
        }
        if (t + 2 < ks) { WVM(4); } else if (t + 1 < ks) { WVM(0); }
        BAR;
    }

    const int rb = tM * 256 + wr * 128 + ((lane >> 4) << 2);
    const int cb = tN * 256 + wc * 64 + l15;
    if (cf32) {
        float* C = (float*)Cv + (size_t)batch * sCb;
        #pragma unroll
        for (int m = 0; m < 8; ++m)
            #pragma unroll
            for (int n = 0; n < 4; ++n)
                #pragma unroll
                for (int j = 0; j < 4; ++j)
                    C[(size_t)(rb + m * 16 + j) * ldc + cb + n * 16] = acc[m][n][j];
    } else {
        u16* C = (u16*)Cv + (size_t)batch * sCb;
        #pragma unroll
        for (int m = 0; m < 8; ++m)
            #pragma unroll
            for (int n = 0; n < 4; ++n)
                #pragma unroll
                for (int j = 0; j < 4; ++j)
                    C[(size_t)(rb + m * 16 + j) * ldc + cb + n * 16] = f2bf(acc[m][n][j]);
    }
}

// ---------- softmax + diagonal-shift ----------
__global__ __launch_bounds__(128) void k_softmax(u16* __restrict__ att,
                                                 const float* __restrict__ attn_b) {
    __shared__ float sv[1000];
    __shared__ float red[2], red2[2];
    const int row = blockIdx.x;
    const int n = row & 1023;
    u16* __restrict__ r = att + (size_t)row * 1024;
    const int tid = threadIdx.x, c8 = tid * 8;
    if (n >= 1000) {
        short8 z = {0, 0, 0, 0, 0, 0, 0, 0};
        *(short8*)&r[c8] = z;
        return;
    }
    short8 v = *(const short8*)&r[c8];
    float f[8];
    float lmax = -1e30f;
    #pragma unroll
    for (int j = 0; j < 8; ++j) {
        int c = c8 + j;
        f[j] = (c < 999) ? bf2f((u16)v[j]) + attn_b[c] : -1e30f;
        lmax = fmaxf(lmax, f[j]);
    }
    #pragma unroll
    for (int o = 32; o > 0; o >>= 1) lmax = fmaxf(lmax, __shfl_xor(lmax, o));
    if ((tid & 63) == 0) red[tid >> 6] = lmax;
    __syncthreads();
    float gmax = fmaxf(red[0], red[1]);
    float lsum = 0.f;
    #pragma unroll
    for (int j = 0; j < 8; ++j) {
        int c = c8 + j;
        float e = (c < 999) ? __expf(f[j] - gmax) : 0.f;
        if (c < 999) sv[c] = e;
        lsum += e;
    }
    #pragma unroll
    for (int o = 32; o > 0; o >>= 1) lsum += __shfl_xor(lsum, o);
    if ((tid & 63) == 0) red2[tid >> 6] = lsum;
    __syncthreads();
    float inv = 1.f / (red2[0] + red2[1]);
    short8 o;
    #pragma unroll
    for (int j = 0; j < 8; ++j) {
        int c = c8 + j;
        float val = 0.f;
        if (c < 1000 && c != n) val = sv[c - (c > n ? 1 : 0)] * inv;
        o[j] = (short)f2bf(val);
    }
    *(short8*)&r[c8] = o;
}

// ---------- transpose: bafT[b][d][m] = all_feat[b][m][768+d] ----------
__global__ __launch_bounds__(256) void k_transpose(const u16* __restrict__ af,
                                                   u16* __restrict__ bafT) {
    __shared__ __attribute__((aligned(16))) u16 t[64 * 64];
    const int mt = blockIdx.x & 15, dt = blockIdx.x >> 4;
    const int b = blockIdx.y;
    const int tid = threadIdx.x;
    const u16* src = af + ((size_t)(b * 1024 + mt * 64)) * 1536 + 768 + dt * 64;
    #pragma unroll
    for (int h = 0; h < 2; ++h) {
        int slot = h * 256 + tid;
        int m = slot >> 3, col16 = slot & 7;
        short8 v = *(const short8*)&src[(size_t)m * 1536 + col16 * 8];
        int key = ((m >> 3) + m) & 7;
        *(short8*)&t[m * 64 + ((col16 ^ key) * 8)] = v;
    }
    __syncthreads();
    u16* dst = bafT + ((size_t)b * 768 + dt * 64) * 1024 + mt * 64;
    #pragma unroll
    for (int h = 0; h < 2; ++h) {
        int slot = h * 256 + tid;
        int d = slot >> 3, m8 = (slot & 7) * 8;
        short8 v;
        #pragma unroll
        for (int j = 0; j < 8; ++j) {
            int m = m8 + j;
            int key = ((m >> 3) + m) & 7;
            v[j] = (short)t[m * 64 + (((d >> 3) ^ key) * 8) + (d & 7)];
        }
        *(short8*)&dst[(size_t)d * 1024 + m8] = v;
    }
}

// ---------- output assembly from f32 gemm3 temp ----------
__global__ __launch_bounds__(256) void k_out(const float* __restrict__ c3,
                                             const float* __restrict__ anchors,
                                             const float* __restrict__ cls_b,
                                             const float* __restrict__ reg_b,
                                             float* __restrict__ out) {
    int i = blockIdx.x * 256 + threadIdx.x;          // 32*1000*77
    if (i >= 2464000) return;
    int o = i % 77;
    int bn = i / 77;
    int n = bn % 1000, b = bn / 1000;
    size_t r = (size_t)(b * 1024 + n) * 256;
    float val;
    if (o < 2)      val = c3[r + o] + cls_b[o];
    else if (o < 4) val = anchors[n * 77 + o];
    else            val = c3[r + o - 2] + reg_b[o - 4] + anchors[n * 77 + o];
    out[i] = val;
}

extern "C" void kernel_launch(void* const* d_in, const int* in_sizes, int n_in,
                              void* d_out, int out_size, void* d_ws, size_t ws_size,
                              hipStream_t stream) {
    const float* x       = (const float*)d_in[0];
    const float* anchors = (const float*)d_in[1];
    const float* conv1_w = (const float*)d_in[2];
    const float* conv1_b = (const float*)d_in[3];
    const float* attn_w  = (const float*)d_in[4];
    const float* attn_b  = (const float*)d_in[5];
    const float* cls_w   = (const float*)d_in[6];
    const float* cls_b   = (const float*)d_in[7];
    const float* reg_w   = (const float*)d_in[8];
    const float* reg_b   = (const float*)d_in[9];
    const int*   cut_xs  = (const int*)d_in[12];
    const void*  invalid = d_in[13];
    float* out = (float*)d_out;

    char* ws = (char*)d_ws;
    u16*   wcat    = (u16*)  (ws + 0);           // 256x1536
    u16*   attn_wb = (u16*)  (ws + 786432);
    u16*   af      = (u16*)  (ws + 2228224);     // all_feat [32][1024][1536]
    u16*   bafT    = (u16*)  (ws + 102891520);
    float* c3f     = (float*)(ws + 102891520);   // reuses bafT after GEMM2
    u16*   att     = (u16*)  (ws + 153223168);
    float* feat    = (float*)(ws + 153223168);   // inside att, dead before GEMM1
    int*   xn      = (int*)  (ws + 155025408);   // inside att
    int*   mflag   = xn + 11000;

    k_prep_attnw<<<2816, 256, 0, stream>>>(attn_w, attn_wb);
    k_prep_wcat<<<1536, 256, 0, stream>>>(cls_w, reg_w, wcat);
    k_detect_mask<<<1, 256, 0, stream>>>((const unsigned char*)invalid, mflag);
    k_prep_xn<<<43, 256, 0, stream>>>(cut_xs, invalid, mflag, xn);
    k_conv<<<dim3(32, 16), 256, 0, stream>>>(x, conv1_w, conv1_b, feat);
    k_gather<<<dim3(256, 32), 384, 0, stream>>>(feat, xn, af);
    // GEMM1: att = af_hi(32768x704,lda1536) x attn_wb(1024x704)^T
    k_g8<<<512, 512, 0, stream>>>(af + 768, 0L, 1536, attn_wb, 0L, 704,
                                  att, 0L, 1024, 4, 512, 512, 11, 0);
    k_softmax<<<32768, 128, 0, stream>>>(att, attn_b);
    k_transpose<<<dim3(192, 32), 256, 0, stream>>>(af, bafT);
    // GEMM2 (batched 32): af_lo = att(1024x1024) x bafT(768x1024)^T
    k_g8<<<384, 512, 0, stream>>>(att, 1048576L, 1024, bafT, 786432L, 1024,
                                  af, 1572864L, 1536, 3, 12, 384, 16, 0);
    // GEMM3: c3f = all_feat(32768x1536,lda1536) x wcat(256x1536)^T (f32 out)
    k_g8<<<128, 512, 0, stream>>>(af, 0L, 1536, wcat, 0L, 1536,
                                  c3f, 0L, 256, 1, 128, 128, 24, 1);
    k_out<<<9625, 256, 0, stream>>>(c3f, anchors, cls_b, reg_b, out);
}

// Round 7
// 351.263 us; speedup vs baseline: 1.1652x; 1.0927x over previous
//
#include <hip/hip_runtime.h>

// LaneATT head, MI355X.
// all_feat af[b][1024][1536] bf16: cols 0:768 = att_feat (GEMM2 C), 768:1536 = baf (gather).
// wcat is 128x1536 matching af col geometry (k 704..767 and 1472..1535 zero).
// Pipeline: k_prep -> conv -> gather(af hi) -> G1=k_g8(af_hi x attn_wb^T -> att)
//  -> softmax(att, regs-only) -> transpose(af_hi -> bafT) -> G2=k_g8(att x bafT^T -> af_lo)
//  -> G3=k_g3(af x wcat^T -> c3f f32, BM=BN=128) -> k_out.
// ws layout (bytes): wcat @0 (393,216) | attn_wb @393,216 (1,441,792)
//  | af @1,835,008 (100,663,296) | bafT @102,498,304 (50,331,648; c3f 16MB reuses base)
//  | att @152,829,952 (67,108,864; feat f32 @152,829,952 + xn @154,632,192 live pre-G1).
//  End 219,938,816.

typedef unsigned short u16;
typedef short short8 __attribute__((ext_vector_type(8)));
typedef float f32x4 __attribute__((ext_vector_type(4)));

__device__ __forceinline__ u16 f2bf(float f) {
    union { float f; unsigned u; } v; v.f = f;
    unsigned r = v.u + 0x7FFFu + ((v.u >> 16) & 1u);
    return (u16)(r >> 16);
}
__device__ __forceinline__ float bf2f(u16 u) {
    union { unsigned u; float f; } v; v.u = ((unsigned)u) << 16;
    return v.f;
}

__device__ __forceinline__ void gload16(const u16* gsrc, u16* ldst) {
    __builtin_amdgcn_global_load_lds(
        (const __attribute__((address_space(1))) unsigned int*)gsrc,
        (__attribute__((address_space(3))) unsigned int*)ldst, 16, 0, 0);
}

#define DSR(d, a, off) asm volatile("ds_read_b128 %0, %1 offset:" #off : "=v"(d) : "v"(a))
#define LGKM0 do { asm volatile("s_waitcnt lgkmcnt(0)" ::: "memory"); \
                   __builtin_amdgcn_sched_barrier(0); } while (0)
#define WVM(n) asm volatile("s_waitcnt vmcnt(" #n ")" ::: "memory")
#define BAR __builtin_amdgcn_s_barrier()

#define MFCL(Aarr, Barr, MH) do { \
    __builtin_amdgcn_s_setprio(1); \
    _Pragma("unroll") \
    for (int m = 0; m < 4; ++m) { \
        _Pragma("unroll") \
        for (int n = 0; n < 4; ++n) \
            acc[(MH) * 4 + m][n] = __builtin_amdgcn_mfma_f32_16x16x32_bf16( \
                Aarr[m], Barr[n], acc[(MH) * 4 + m][n], 0, 0, 0); \
    } \
    __builtin_amdgcn_s_setprio(0); } while (0)

// ---------- fused prep: [0,2816) attnw | [2816,3584) wcat | [3584,3627) xn ----------
__global__ __launch_bounds__(256) void k_prep(const float* __restrict__ attn_w,
                                              const float* __restrict__ cls_w,
                                              const float* __restrict__ reg_w,
                                              const int* __restrict__ cut_xs,
                                              const void* __restrict__ mask,
                                              u16* __restrict__ attn_wb,
                                              u16* __restrict__ wcat,
                                              int* __restrict__ xn) {
    const int blk = blockIdx.x, tid = threadIdx.x;
    if (blk < 2816) {
        int i = blk * 256 + tid;                    // 1024*704 = 720896 exactly
        int r = i / 704;
        attn_wb[i] = (r < 999) ? f2bf(attn_w[i]) : (u16)0;
        return;
    }
    if (blk < 3584) {
        int i = (blk - 2816) * 256 + tid;           // 128*1536 = 196608 exactly
        int o = i / 1536, k = i - o * 1536;
        int ksrc = -1;
        if (k < 704) ksrc = k;
        else if (k >= 768 && k < 1472) ksrc = k - 64;
        float v = 0.f;
        if (ksrc >= 0) {
            if (o < 2) v = cls_w[o * 1408 + ksrc];
            else if (o < 75) v = reg_w[(o - 2) * 1408 + ksrc];
        }
        wcat[i] = f2bf(v);
        return;
    }
    // xn blocks: redundant per-block mask-dtype detection (bool vs int32), then fill.
    const unsigned char* m8 = (const unsigned char*)mask;
    int any = 0;
    for (int i = tid; i < 11000; i += 256)
        if ((i & 3) && m8[i]) any = 1;
    any = __any(any) ? 1 : 0;
    __shared__ int sh[4];
    if ((tid & 63) == 0) sh[tid >> 6] = any;
    __syncthreads();
    int isb8 = sh[0] | sh[1] | sh[2] | sh[3];
    int i = (blk - 3584) * 256 + tid;
    if (i < 11000) {
        int inv = isb8 ? (int)m8[i] : ((const int*)mask)[i];
        int n = i / 11, y = i - n * 11;
        xn[i] = inv ? -1 : cut_xs[n * 704 + y];
    }
}

// ---------- conv 1x1 ----------
__global__ __launch_bounds__(256) void k_conv(const float* __restrict__ x,
                                              const float* __restrict__ w1,
                                              const float* __restrict__ b1,
                                              float* __restrict__ feat) {
    __shared__ float wl[4][512];
    const int b = blockIdx.x, og = blockIdx.y;
    for (int i = threadIdx.x; i < 4 * 512; i += 256)
        wl[i >> 9][i & 511] = w1[(og * 4 + (i >> 9)) * 512 + (i & 511)];
    __syncthreads();
    const int p = threadIdx.x;
    if (p >= 220) return;
    const float* xb = x + (size_t)b * 512 * 220 + p;
    float a0 = 0.f, a1 = 0.f, a2 = 0.f, a3 = 0.f;
    #pragma unroll 4
    for (int c = 0; c < 512; ++c) {
        float xv = xb[(size_t)c * 220];
        a0 = fmaf(xv, wl[0][c], a0);
        a1 = fmaf(xv, wl[1][c], a1);
        a2 = fmaf(xv, wl[2][c], a2);
        a3 = fmaf(xv, wl[3][c], a3);
    }
    float* fo = feat + (size_t)b * 14080 + (og * 4) * 220 + p;
    fo[0]   = a0 + b1[og * 4 + 0];
    fo[220] = a1 + b1[og * 4 + 1];
    fo[440] = a2 + b1[og * 4 + 2];
    fo[660] = a3 + b1[og * 4 + 3];
}

// ---------- gather -> all_feat upper half ----------
__global__ __launch_bounds__(384) void k_gather(const float* __restrict__ feat,
                                                const int* __restrict__ xn,
                                                u16* __restrict__ af) {
    const int b = blockIdx.y, t = threadIdx.x;
    const int a = t / 96, r = t - a * 96;
    const int n = blockIdx.x * 4 + a;
    const int d8 = r * 8;
    const float* fb = feat + (size_t)b * 14080;
    short8 o = {0, 0, 0, 0, 0, 0, 0, 0};
    #pragma unroll
    for (int j = 0; j < 8; ++j) {
        int d = d8 + j;
        float v = 0.f;
        if (n < 1000 && d < 704) {
            int c = d / 11, y = d - c * 11;
            int xv = xn[n * 11 + y];
            if (xv >= 0) v = fb[c * 220 + y * 20 + xv];
        }
        o[j] = (short)f2bf(v);
    }
    *(short8*)&af[((size_t)b * 1024 + n) * 1536 + 768 + d8] = o;
}

// ---------- 8-phase 256x256 bf16 GEMM engine (unchanged from round 6) ----------
__global__ __launch_bounds__(512, 2) void k_g8(const u16* __restrict__ A, long sAb, int lda,
                                               const u16* __restrict__ Bt, long sBb, int ldb,
                                               void* __restrict__ Cv, long sCb, int ldc,
                                               int ntN, int tpb, int nwg, int ks, int cf32) {
    __shared__ __attribute__((aligned(16))) u16 LDS[65536];   // 128 KB
    const int bid = blockIdx.x;
    const int cpx = nwg >> 3;
    const int logical = (bid & 7) * cpx + (bid >> 3);
    const int batch = logical / tpb;
    const int t0 = logical - batch * tpb;
    const int tM = t0 / ntN, tN = t0 - tM * ntN;
    A  += (size_t)batch * sAb;
    Bt += (size_t)batch * sBb;

    const int tid = threadIdx.x;
    const int lane = tid & 63, w = tid >> 6;
    const int wr = w >> 2, wc = w & 3;
    const int l15 = lane & 15;
    const int lkswz = ((lane >> 4) ^ ((l15 >> 1) & 3)) * 8;
    const u16* Abase = A + (size_t)tM * 256 * lda;
    const u16* Bbase = Bt + (size_t)tN * 256 * ldb;
    const int srow = tid >> 2;
    const int sgc = (((tid & 3) ^ ((tid >> 3) & 3)) * 8);

    f32x4 acc[8][4] = {};

    auto SGA = [&](int t, int kh) {
        const int base = ((t & 1) * 2 + kh) * 8192;
        const u16* g = Abase + (size_t)srow * lda + t * 64 + kh * 32 + sgc;
        gload16(g, &LDS[base + tid * 8]);
        gload16(g + (size_t)128 * lda, &LDS[base + 4096 + tid * 8]);
    };
    auto SGB = [&](int t, int kh) {
        const int base = 32768 + ((t & 1) * 2 + kh) * 8192;
        const u16* g = Bbase + (size_t)srow * ldb + t * 64 + kh * 32 + sgc;
        gload16(g, &LDS[base + tid * 8]);
        gload16(g + (size_t)128 * ldb, &LDS[base + 4096 + tid * 8]);
    };

    SGA(0, 0); SGB(0, 0); SGA(0, 1); SGB(0, 1);
    if (ks > 1) { SGA(1, 0); SGB(1, 0); WVM(4); } else { WVM(0); }
    BAR;

    const unsigned aAl = (unsigned)(size_t)&LDS[(wr * 128 + l15) * 32 + lkswz];
    const unsigned aBl = (unsigned)(size_t)&LDS[32768 + (wc * 64 + l15) * 32 + lkswz];

    for (int t = 0; t < ks; ++t) {
        const unsigned bo = (unsigned)((t & 1) * 2) * 16384u;
        short8 av[4], bk[4];
        if (t + 1 < ks) SGA(t + 1, 1);
        {
            unsigned aA = aAl + bo, aB = aBl + bo;
            DSR(bk[0], aB, 0); DSR(bk[1], aB, 1024); DSR(bk[2], aB, 2048); DSR(bk[3], aB, 3072);
            DSR(av[0], aA, 0); DSR(av[1], aA, 1024); DSR(av[2], aA, 2048); DSR(av[3], aA, 3072);
            LGKM0;
            MFCL(av, bk, 0);
        }
        BAR;
        if (t + 1 < ks) SGB(t + 1, 1);
        {
            unsigned aA = aAl + bo;
            DSR(av[0], aA, 4096); DSR(av[1], aA, 5120); DSR(av[2], aA, 6144); DSR(av[3], aA, 7168);
            LGKM0;
            MFCL(av, bk, 1);
        }
        BAR;
        if (t + 2 < ks) SGA(t + 2, 0);
        {
            unsigned aA = aAl + bo + 16384u, aB = aBl + bo + 16384u;
            DSR(bk[0], aB, 0); DSR(bk[1], aB, 1024); DSR(bk[2], aB, 2048); DSR(bk[3], aB, 3072);
            DSR(av[0], aA, 0); DSR(av[1], aA, 1024); DSR(av[2], aA, 2048); DSR(av[3], aA, 3072);
            LGKM0;
            MFCL(av, bk, 0);
        }
        BAR;
        if (t + 2 < ks) SGB(t + 2, 0);
        {
            unsigned aA = aAl + bo + 16384u;
            DSR(av[0], aA, 4096); DSR(av[1], aA, 5120); DSR(av[2], aA, 6144); DSR(av[3], aA, 7168);
            LGKM0;
            MFCL(av, bk, 1);
        }
        if (t + 2 < ks) { WVM(4); } else if (t + 1 < ks) { WVM(0); }
        BAR;
    }

    const int rb = tM * 256 + wr * 128 + ((lane >> 4) << 2);
    const int cb = tN * 256 + wc * 64 + l15;
    if (cf32) {
        float* C = (float*)Cv + (size_t)batch * sCb;
        #pragma unroll
        for (int m = 0; m < 8; ++m)
            #pragma unroll
            for (int n = 0; n < 4; ++n)
                #pragma unroll
                for (int j = 0; j < 4; ++j)
                    C[(size_t)(rb + m * 16 + j) * ldc + cb + n * 16] = acc[m][n][j];
    } else {
        u16* C = (u16*)Cv + (size_t)batch * sCb;
        #pragma unroll
        for (int m = 0; m < 8; ++m)
            #pragma unroll
            for (int n = 0; n < 4; ++n)
                #pragma unroll
                for (int j = 0; j < 4; ++j)
                    C[(size_t)(rb + m * 16 + j) * ldc + cb + n * 16] = f2bf(acc[m][n][j]);
    }
}

// ---------- GEMM3: BM=128, BN=128, 8-phase, loads/stage=1 -> vmcnt(2) ----------
// c3f[32768][128] f32 = af(32768x1536) x wcat(128x1536)^T. Grid 256, 64KB LDS, 2 blk/CU.
__global__ __launch_bounds__(512, 4) void k_g3(const u16* __restrict__ A, int lda,
                                               const u16* __restrict__ Bt,
                                               float* __restrict__ C,
                                               int nwg, int ks) {
    __shared__ __attribute__((aligned(16))) u16 LDS[32768];   // 64 KB
    const int bid = blockIdx.x;
    const int cpx = nwg >> 3;
    const int tM = (bid & 7) * cpx + (bid >> 3);
    const int tid = threadIdx.x;
    const int lane = tid & 63, w = tid >> 6;
    const int wr2 = w >> 2, wc2 = w & 3;              // wave tile: 64 rows x 32 cols
    const int l15 = lane & 15;
    const int lkswz = ((lane >> 4) ^ ((l15 >> 1) & 3)) * 8;
    const u16* Abase = A + (size_t)tM * 128 * lda;
    const int srow = tid >> 2;
    const int sgc = (((tid & 3) ^ ((tid >> 3) & 3)) * 8);

    f32x4 acc[4][2] = {};

    auto SGA = [&](int t, int kh) {
        const int base = ((t & 1) * 2 + kh) * 4096;
        gload16(Abase + (size_t)srow * lda + t * 64 + kh * 32 + sgc, &LDS[base + tid * 8]);
    };
    auto SGB = [&](int t, int kh) {
        const int base = 16384 + ((t & 1) * 2 + kh) * 4096;
        gload16(Bt + (size_t)srow * 1536 + t * 64 + kh * 32 + sgc, &LDS[base + tid * 8]);
    };

    SGA(0, 0); SGB(0, 0); SGA(0, 1); SGB(0, 1);
    if (ks > 1) { SGA(1, 0); SGB(1, 0); WVM(2); } else { WVM(0); }
    BAR;

    const unsigned aAl = (unsigned)(size_t)&LDS[(wr2 * 64 + l15) * 32 + lkswz];
    const unsigned aBl = (unsigned)(size_t)&LDS[16384 + (wc2 * 32 + l15) * 32 + lkswz];

    for (int t = 0; t < ks; ++t) {
        const unsigned bo = (unsigned)(t & 1) * 16384u;
        short8 av[2], bk[2];
        if (t + 1 < ks) SGA(t + 1, 1);
        {
            unsigned aA = aAl + bo, aB = aBl + bo;
            DSR(bk[0], aB, 0); DSR(bk[1], aB, 1024);
            DSR(av[0], aA, 0); DSR(av[1], aA, 1024);
            LGKM0;
            __builtin_amdgcn_s_setprio(1);
            acc[0][0] = __builtin_amdgcn_mfma_f32_16x16x32_bf16(av[0], bk[0], acc[0][0], 0, 0, 0);
            acc[0][1] = __builtin_amdgcn_mfma_f32_16x16x32_bf16(av[0], bk[1], acc[0][1], 0, 0, 0);
            acc[1][0] = __builtin_amdgcn_mfma_f32_16x16x32_bf16(av[1], bk[0], acc[1][0], 0, 0, 0);
            acc[1][1] = __builtin_amdgcn_mfma_f32_16x16x32_bf16(av[1], bk[1], acc[1][1], 0, 0, 0);
            __builtin_amdgcn_s_setprio(0);
        }
        BAR;
        if (t + 1 < ks) SGB(t + 1, 1);
        {
            unsigned aA = aAl + bo;
            DSR(av[0], aA, 2048); DSR(av[1], aA, 3072);
            LGKM0;
            __builtin_amdgcn_s_setprio(1);
            acc[2][0] = __builtin_amdgcn_mfma_f32_16x16x32_bf16(av[0], bk[0], acc[2][0], 0, 0, 0);
            acc[2][1] = __builtin_amdgcn_mfma_f32_16x16x32_bf16(av[0], bk[1], acc[2][1], 0, 0, 0);
            acc[3][0] = __builtin_amdgcn_mfma_f32_16x16x32_bf16(av[1], bk[0], acc[3][0], 0, 0, 0);
            acc[3][1] = __builtin_amdgcn_mfma_f32_16x16x32_bf16(av[1], bk[1], acc[3][1], 0, 0, 0);
            __builtin_amdgcn_s_setprio(0);
        }
        BAR;
        if (t + 2 < ks) SGA(t + 2, 0);
        {
            unsigned aA = aAl + bo + 8192u, aB = aBl + bo + 8192u;
            DSR(bk[0], aB, 0); DSR(bk[1], aB, 1024);
            DSR(av[0], aA, 0); DSR(av[1], aA, 1024);
            LGKM0;
            __builtin_amdgcn_s_setprio(1);
            acc[0][0] = __builtin_amdgcn_mfma_f32_16x16x32_bf16(av[0], bk[0], acc[0][0], 0, 0, 0);
            acc[0][1] = __builtin_amdgcn_mfma_f32_16x16x32_bf16(av[0], bk[1], acc[0][1], 0, 0, 0);
            acc[1][0] = __builtin_amdgcn_mfma_f32_16x16x32_bf16(av[1], bk[0], acc[1][0], 0, 0, 0);
            acc[1][1] = __builtin_amdgcn_mfma_f32_16x16x32_bf16(av[1], bk[1], acc[1][1], 0, 0, 0);
            __builtin_amdgcn_s_setprio(0);
        }
        BAR;
        if (t + 2 < ks) SGB(t + 2, 0);
        {
            unsigned aA = aAl + bo + 8192u;
            DSR(av[0], aA, 2048); DSR(av[1], aA, 3072);
            LGKM0;
            __builtin_amdgcn_s_setprio(1);
            acc[2][0] = __builtin_amdgcn_mfma_f32_16x16x32_bf16(av[0], bk[0], acc[2][0], 0, 0, 0);
            acc[2][1] = __builtin_amdgcn_mfma_f32_16x16x32_bf16(av[0], bk[1], acc[2][1], 0, 0, 0);
            acc[3][0] = __builtin_amdgcn_mfma_f32_16x16x32_bf16(av[1], bk[0], acc[3][0], 0, 0, 0);
            acc[3][1] = __builtin_amdgcn_mfma_f32_16x16x32_bf16(av[1], bk[1], acc[3][1], 0, 0, 0);
            __builtin_amdgcn_s_setprio(0);
        }
        if (t + 2 < ks) { WVM(2); } else if (t + 1 < ks) { WVM(0); }
        BAR;
    }

    const int rb = tM * 128 + wr2 * 64 + ((lane >> 4) << 2);
    const int cb = wc2 * 32 + l15;
    #pragma unroll
    for (int m = 0; m < 4; ++m)
        #pragma unroll
        for (int n = 0; n < 2; ++n)
            #pragma unroll
            for (int j = 0; j < 4; ++j)
                C[(size_t)(rb + m * 16 + j) * 128 + cb + n * 16] = acc[m][n][j];
}

// ---------- softmax + diagonal-shift: registers only, shfl boundary handoff ----------
__global__ __launch_bounds__(128) void k_softmax(u16* __restrict__ att,
                                                 const float* __restrict__ attn_b) {
    __shared__ float red[2], red2[2], bnd;
    const int row = blockIdx.x;
    const int n = row & 1023;
    u16* __restrict__ r = att + (size_t)row * 1024;
    const int tid = threadIdx.x, c8 = tid * 8;
    const int lane = tid & 63, wid = tid >> 6;
    if (n >= 1000) {
        short8 z = {0, 0, 0, 0, 0, 0, 0, 0};
        *(short8*)&r[c8] = z;
        return;
    }
    short8 v = *(const short8*)&r[c8];
    float f[8];
    float lmax = -1e30f;
    #pragma unroll
    for (int j = 0; j < 8; ++j) {
        int c = c8 + j;
        f[j] = (c < 999) ? bf2f((u16)v[j]) + attn_b[c] : -1e30f;
        lmax = fmaxf(lmax, f[j]);
    }
    #pragma unroll
    for (int o = 32; o > 0; o >>= 1) lmax = fmaxf(lmax, __shfl_xor(lmax, o));
    if (lane == 0) red[wid] = lmax;
    __syncthreads();
    float gmax = fmaxf(red[0], red[1]);
    float e[8];
    float lsum = 0.f;
    #pragma unroll
    for (int j = 0; j < 8; ++j) {
        int c = c8 + j;
        e[j] = (c < 999) ? __expf(f[j] - gmax) : 0.f;
        lsum += e[j];
    }
    #pragma unroll
    for (int o = 32; o > 0; o >>= 1) lsum += __shfl_xor(lsum, o);
    if (lane == 0) red2[wid] = lsum;
    if (lane == 63 && wid == 0) bnd = e[7];
    __syncthreads();
    float inv = 1.f / (red2[0] + red2[1]);
    float prev = __shfl_up(e[7], 1);
    if (lane == 0) prev = (wid == 1) ? bnd : 0.f;
    short8 o;
    #pragma unroll
    for (int j = 0; j < 8; ++j) {
        int c = c8 + j;
        float pm1 = (j == 0) ? prev : e[j - 1];
        float val = 0.f;
        if (c < 1000) {
            if (c < n) val = e[j] * inv;
            else if (c > n) val = pm1 * inv;
        }
        o[j] = (short)f2bf(val);
    }
    *(short8*)&r[c8] = o;
}

// ---------- transpose: bafT[b][d][m] = af[b][m][768+d] ----------
__global__ __launch_bounds__(256) void k_transpose(const u16* __restrict__ af,
                                                   u16* __restrict__ bafT) {
    __shared__ __attribute__((aligned(16))) u16 t[64 * 64];
    const int mt = blockIdx.x & 15, dt = blockIdx.x >> 4;
    const int b = blockIdx.y;
    const int tid = threadIdx.x;
    const u16* src = af + ((size_t)(b * 1024 + mt * 64)) * 1536 + 768 + dt * 64;
    #pragma unroll
    for (int h = 0; h < 2; ++h) {
        int slot = h * 256 + tid;
        int m = slot >> 3, col16 = slot & 7;
        short8 v = *(const short8*)&src[(size_t)m * 1536 + col16 * 8];
        int key = ((m >> 3) + m) & 7;
        *(short8*)&t[m * 64 + ((col16 ^ key) * 8)] = v;
    }
    __syncthreads();
    u16* dst = bafT + ((size_t)b * 768 + dt * 64) * 1024 + mt * 64;
    #pragma unroll
    for (int h = 0; h < 2; ++h) {
        int slot = h * 256 + tid;
        int d = slot >> 3, m8 = (slot & 7) * 8;
        short8 v;
        #pragma unroll
        for (int j = 0; j < 8; ++j) {
            int m = m8 + j;
            int key = ((m >> 3) + m) & 7;
            v[j] = (short)t[m * 64 + (((d >> 3) ^ key) * 8) + (d & 7)];
        }
        *(short8*)&dst[(size_t)d * 1024 + m8] = v;
    }
}

// ---------- output assembly from f32 gemm3 temp (ldc=128) ----------
__global__ __launch_bounds__(256) void k_out(const float* __restrict__ c3,
                                             const float* __restrict__ anchors,
                                             const float* __restrict__ cls_b,
                                             const float* __restrict__ reg_b,
                                             float* __restrict__ out) {
    int i = blockIdx.x * 256 + threadIdx.x;          // 32*1000*77
    if (i >= 2464000) return;
    int o = i % 77;
    int bn = i / 77;
    int n = bn % 1000, b = bn / 1000;
    size_t r = (size_t)(b * 1024 + n) * 128;
    float val;
    if (o < 2)      val = c3[r + o] + cls_b[o];
    else if (o < 4) val = anchors[n * 77 + o];
    else            val = c3[r + o - 2] + reg_b[o - 4] + anchors[n * 77 + o];
    out[i] = val;
}

extern "C" void kernel_launch(void* const* d_in, const int* in_sizes, int n_in,
                              void* d_out, int out_size, void* d_ws, size_t ws_size,
                              hipStream_t stream) {
    const float* x       = (const float*)d_in[0];
    const float* anchors = (const float*)d_in[1];
    const float* conv1_w = (const float*)d_in[2];
    const float* conv1_b = (const float*)d_in[3];
    const float* attn_w  = (const float*)d_in[4];
    const float* attn_b  = (const float*)d_in[5];
    const float* cls_w   = (const float*)d_in[6];
    const float* cls_b   = (const float*)d_in[7];
    const float* reg_w   = (const float*)d_in[8];
    const float* reg_b   = (const float*)d_in[9];
    const int*   cut_xs  = (const int*)d_in[12];
    const void*  invalid = d_in[13];
    float* out = (float*)d_out;

    char* ws = (char*)d_ws;
    u16*   wcat    = (u16*)  (ws + 0);           // 128x1536
    u16*   attn_wb = (u16*)  (ws + 393216);
    u16*   af      = (u16*)  (ws + 1835008);     // [32][1024][1536]
    u16*   bafT    = (u16*)  (ws + 102498304);
    float* c3f     = (float*)(ws + 102498304);   // 16MB, reuses bafT after G2
    u16*   att     = (u16*)  (ws + 152829952);
    float* feat    = (float*)(ws + 152829952);   // inside att, dead before G1
    int*   xn      = (int*)  (ws + 154632192);   // inside att

    k_prep<<<3627, 256, 0, stream>>>(attn_w, cls_w, reg_w, cut_xs, invalid,
                                     attn_wb, wcat, xn);
    k_conv<<<dim3(32, 16), 256, 0, stream>>>(x, conv1_w, conv1_b, feat);
    k_gather<<<dim3(256, 32), 384, 0, stream>>>(feat, xn, af);
    // G1: att = af_hi(32768x704,lda1536) x attn_wb(1024x704)^T
    k_g8<<<512, 512, 0, stream>>>(af + 768, 0L, 1536, attn_wb, 0L, 704,
                                  att, 0L, 1024, 4, 512, 512, 11, 0);
    k_softmax<<<32768, 128, 0, stream>>>(att, attn_b);
    k_transpose<<<dim3(192, 32), 256, 0, stream>>>(af, bafT);
    // G2 (batched 32): af_lo = att(1024x1024) x bafT(768x1024)^T
    k_g8<<<384, 512, 0, stream>>>(att, 1048576L, 1024, bafT, 786432L, 1024,
                                  af, 1572864L, 1536, 3, 12, 384, 16, 0);
    // G3: c3f = af(32768x1536) x wcat(128x1536)^T, BM=BN=128
    k_g3<<<256, 512, 0, stream>>>(af, 1536, wcat, c3f, 256, 24);
    k_out<<<9625, 256, 0, stream>>>(c3f, anchors, cls_b, reg_b, out);
}